// Round 15
// baseline (166.304 us; speedup 1.0000x reference)
//
#include <hip/hip_runtime.h>

typedef float f32x4 __attribute__((ext_vector_type(4)));
typedef __bf16 bf16x8 __attribute__((ext_vector_type(8)));
typedef __bf16 bf16x4 __attribute__((ext_vector_type(4)));

#define B_ 4
#define T_ 2048
#define D_ 1024
#define H_ 16
#define HD_ 64

__device__ __forceinline__ void gload_lds16(const void* g, void* l) {
  __builtin_amdgcn_global_load_lds(
      (const __attribute__((address_space(1))) void*)g,
      (__attribute__((address_space(3))) void*)l, 16, 0, 0);
}

// ---------------------------------------------------------------- convert x
__global__ __launch_bounds__(256) void k_cvt_f32_bf16(
    const float* __restrict__ in, __bf16* __restrict__ out, int n4) {
  int i = blockIdx.x * blockDim.x + threadIdx.x;
  int stride = gridDim.x * blockDim.x;
  for (; i < n4; i += stride) {
    float4 v = reinterpret_cast<const float4*>(in)[i];
    bf16x4 o = { (__bf16)v.x, (__bf16)v.y, (__bf16)v.z, (__bf16)v.w };
    reinterpret_cast<bf16x4*>(out)[i] = o;
  }
}

// ------------------------------------------- transpose (+convert) to bf16
template <typename Tin>
__global__ __launch_bounds__(256) void k_transpose_bf16(
    const Tin* __restrict__ in, __bf16* __restrict__ out,
    int R, int C, long inb, long outb) {
  __shared__ alignas(16) __bf16 lds[64 * 68];
  const int t = threadIdx.x;
  in  += (long)blockIdx.z * inb;
  out += (long)blockIdx.z * outb;
  const int r0 = blockIdx.y * 64, c0 = blockIdx.x * 64;
#pragma unroll
  for (int i = 0; i < 16; ++i) {
    int e = i * 256 + t, row = e >> 6, col = e & 63;
    lds[row * 68 + col] = (__bf16)(float)in[(long)(r0 + row) * C + c0 + col];
  }
  __syncthreads();
#pragma unroll
  for (int i = 0; i < 16; ++i) {
    int e = i * 256 + t, orow = e >> 6, ocol = e & 63;
    out[(long)(c0 + orow) * R + r0 + ocol] = lds[ocol * 68 + orow];
  }
}

// ---------------------------------------------------------------- GEMM (bt)
// 128x128 tile, BK=32, 256 thr. 3-DEEP LDS RING with full-tile-lead
// counted vmcnt (T4): while computing tile kt, tile kt+1 sits fully staged
// in the ring and tile kt+2 is being issued -- vmcnt(4) at the tile top
// drains exactly kt's 4 loads and keeps kt+1's 4 in flight. Loads are
// NEVER drained to 0 in the loop (the round-6..14 2-phase drain stall was
// ~70% of the critical path per m233). 48KB LDS -> 3 blocks/CU resident.
// One barrier per K-tile: publishes tile kt (every wave vmcnt-waited
// before it) and WAR-protects buf[(kt+2)%3] (last read in tile kt-1).
// XOR-swizzled LDS via pre-swizzled global source + XOR'd read slot.
template <int EPI>
__global__ __launch_bounds__(256) void k_gemm_bt(
    const __bf16* __restrict__ A, const __bf16* __restrict__ Bt,
    const float* __restrict__ bias, void* __restrict__ Cout,
    __bf16* __restrict__ vout, int M, int N, int K) {
  __shared__ alignas(16) __bf16 As[3][128 * 32];
  __shared__ alignas(16) __bf16 Bs[3][128 * 32];
  const int t = threadIdx.x;
  const int w = t >> 6, l = t & 63;
  const int g = l >> 4, r16 = l & 15;
  const int wr = w >> 1, wc = w & 1;
  const int m0 = blockIdx.y * 128, n0 = blockIdx.x * 128;

  f32x4 acc[4][4];
#pragma unroll
  for (int i = 0; i < 4; ++i)
#pragma unroll
    for (int j = 0; j < 4; ++j) acc[i][j] = (f32x4){0.f, 0.f, 0.f, 0.f};

  const int arow = t >> 2;                                  // 0..63
  const int acol = ((t & 3) ^ ((t >> 3) & 3)) * 8;          // pre-swizzled src
  const char* Ag = (const char*)(A + (long)(m0 + arow) * K + acol);
  const char* Bg = (const char*)(Bt + (long)(n0 + arow) * K + acol);
  const long rowskip = (long)64 * K * 2;
  const int rdsw = (g ^ ((r16 >> 1) & 3)) * 8;              // read-side slot

  auto stage = [&](int buf, int ktile) {
    const long koff = (long)ktile * 64;                     // 32 cols * 2B
    char* AsW = (char*)As[buf] + w * 1024;
    char* BsW = (char*)Bs[buf] + w * 1024;
    gload_lds16(Ag + koff, AsW);
    gload_lds16(Ag + koff + rowskip, AsW + 4096);
    gload_lds16(Bg + koff, BsW);
    gload_lds16(Bg + koff + rowskip, BsW + 4096);
  };

  const int NT = K >> 5;                 // 32 K-tiles
  stage(0, 0);                           // prologue: 2-tile lead
  stage(1, 1);

  for (int kt = 0; kt < NT; ++kt) {
    asm volatile("s_waitcnt vmcnt(4)" ::: "memory");  // tile kt landed
    __builtin_amdgcn_sched_barrier(0);
    __builtin_amdgcn_s_barrier();        // publish kt; WAR for ring slot
    __builtin_amdgcn_sched_barrier(0);
    const int kn = (kt + 2 < NT) ? kt + 2 : NT - 1;   // tail: dummy re-stage
    stage((kt + 2) % 3, kn);
    const __bf16* Ab = As[kt % 3];
    const __bf16* Bb = Bs[kt % 3];
    bf16x8 af[4], bfr[4];
#pragma unroll
    for (int mi = 0; mi < 4; ++mi)
      af[mi] = *reinterpret_cast<const bf16x8*>(
          &Ab[(wr * 64 + mi * 16 + r16) * 32 + rdsw]);
#pragma unroll
    for (int ni = 0; ni < 4; ++ni)
      bfr[ni] = *reinterpret_cast<const bf16x8*>(
          &Bb[(wc * 64 + ni * 16 + r16) * 32 + rdsw]);
    __builtin_amdgcn_s_setprio(1);
#pragma unroll
    for (int mi = 0; mi < 4; ++mi)
#pragma unroll
      for (int ni = 0; ni < 4; ++ni)
        acc[mi][ni] = __builtin_amdgcn_mfma_f32_16x16x32_bf16(af[mi], bfr[ni], acc[mi][ni], 0, 0, 0);
    __builtin_amdgcn_s_setprio(0);
  }
  asm volatile("s_waitcnt vmcnt(0)" ::: "memory");  // drain dummies pre-exit

  if (EPI == 0) {
    const int which = n0 >> 10;          // block-uniform (128 | 1024)
    __bf16* qkvb = (__bf16*)Cout;
#pragma unroll
    for (int mi = 0; mi < 4; ++mi) {
#pragma unroll
      for (int ni = 0; ni < 4; ++ni) {
        const int n = n0 + wc * 64 + ni * 16 + r16;
        const float bv = bias[n];
        f32x4 c = acc[mi][ni];
        const int rem = n & 1023, h = rem >> 6, hd = rem & 63;
        const int mbase = m0 + wr * 64 + mi * 16 + g * 4;
        const int b = mbase >> 11, tt0 = mbase & 2047;
        if (which < 2) {
#pragma unroll
          for (int r = 0; r < 4; ++r)
            qkvb[((long)((which * B_ + b) * H_ + h) * T_ + tt0 + r) * HD_ + hd] =
                (__bf16)(c[r] + bv);
        } else {
          bf16x4 pk = { (__bf16)(c[0] + bv), (__bf16)(c[1] + bv),
                        (__bf16)(c[2] + bv), (__bf16)(c[3] + bv) };
          *reinterpret_cast<bf16x4*>(
              &vout[(((long)b * H_ + h) * HD_ + hd) * T_ + tt0]) = pk;
        }
      }
    }
  } else {
    float* O = (float*)Cout;
#pragma unroll
    for (int mi = 0; mi < 4; ++mi) {
#pragma unroll
      for (int ni = 0; ni < 4; ++ni) {
        const int n = n0 + wc * 64 + ni * 16 + r16;
        const float bv = bias[n];
        f32x4 c = acc[mi][ni];
        const int mbase = m0 + wr * 64 + mi * 16 + g * 4;
#pragma unroll
        for (int r = 0; r < 4; ++r) O[(long)(mbase + r) * N + n] = c[r] + bv;
      }
    }
  }
}

// ---------------------------------------------------------------- attention
// (round-11 version, the measured optimum of this family)
__device__ __forceinline__ void soft_side(
    const f32x4 (&s)[4], float& lrun, bool diag, int qrel,
    int g, int r16, bf16x8& pa0, bf16x8& pa1) {
  float p[4][4];
#pragma unroll
  for (int nf = 0; nf < 4; ++nf) {
#pragma unroll
    for (int rr = 0; rr < 4; ++rr) {
      float x = s[nf][rr];
      if (diag) x = (nf * 16 + 4 * g + rr <= qrel + r16) ? x : -1e30f;
      p[nf][rr] = __builtin_amdgcn_exp2f(x);  // 2^-1e30 -> +0
    }
  }
  const float ps0 = (p[0][0] + p[0][1]) + (p[0][2] + p[0][3]);
  const float ps1 = (p[1][0] + p[1][1]) + (p[1][2] + p[1][3]);
  const float ps2 = (p[2][0] + p[2][1]) + (p[2][2] + p[2][3]);
  const float ps3 = (p[3][0] + p[3][1]) + (p[3][2] + p[3][3]);
  lrun += (ps0 + ps1) + (ps2 + ps3);

  unsigned u[4][2];
#pragma unroll
  for (int nf = 0; nf < 4; ++nf) {
    asm("v_cvt_pk_bf16_f32 %0, %1, %2"
        : "=v"(u[nf][0]) : "v"(p[nf][0]), "v"(p[nf][1]));
    asm("v_cvt_pk_bf16_f32 %0, %1, %2"
        : "=v"(u[nf][1]) : "v"(p[nf][2]), "v"(p[nf][3]));
  }
#pragma unroll
  for (int j = 0; j < 2; ++j) {
    asm("v_permlane32_swap_b32 %0, %1" : "+v"(u[0][j]), "+v"(u[1][j]));
    asm("v_permlane32_swap_b32 %0, %1" : "+v"(u[2][j]), "+v"(u[3][j]));
  }
#pragma unroll
  for (int j = 0; j < 2; ++j) {
    asm("v_permlane16_swap_b32 %0, %1" : "+v"(u[0][j]), "+v"(u[1][j]));
    asm("v_permlane16_swap_b32 %0, %1" : "+v"(u[2][j]), "+v"(u[3][j]));
  }
  union PU { unsigned w[4]; bf16x8 v; };
  PU a0, a1;
  a0.w[0] = u[0][0]; a0.w[1] = u[0][1]; a0.w[2] = u[1][0]; a0.w[3] = u[1][1];
  a1.w[0] = u[2][0]; a1.w[1] = u[2][1]; a1.w[2] = u[3][0]; a1.w[3] = u[3][1];
  pa0 = a0.v;
  pa1 = a1.v;
}

__global__ __launch_bounds__(256) void k_attn(
    const __bf16* __restrict__ q, const __bf16* __restrict__ k,
    const __bf16* __restrict__ vt, __bf16* __restrict__ o) {
  __shared__ alignas(16) __bf16 Ks[2][64 * 64];
  __shared__ alignas(16) __bf16 Vs[2][64 * 64];
  const int t = threadIdx.x, w = t >> 6, l = t & 63;
  const int g = l >> 4, r16 = l & 15;
  const int bh = blockIdx.x;
  const int qt = 31 - blockIdx.y;
  const int qbase = qt * 64 + w * 16;
  const float sc = 0.125f * 1.44269504088896341f;  // 1/sqrt(64) * log2(e)

  auto scale8 = [&](bf16x8 v) {
    bf16x8 r;
#pragma unroll
    for (int j = 0; j < 8; ++j) r[j] = (__bf16)((float)v[j] * sc);
    return r;
  };
  const __bf16* qp = q + ((long)bh * T_ + qbase + r16) * HD_ + g * 8;
  const bf16x8 aq0 = scale8(*reinterpret_cast<const bf16x8*>(qp));
  const bf16x8 aq1 = scale8(*reinterpret_cast<const bf16x8*>(qp + 32));

  f32x4 oacc[4];
  float lrun = 0.f;
#pragma unroll
  for (int i = 0; i < 4; ++i) oacc[i] = (f32x4){0.f, 0.f, 0.f, 0.f};

  const int srow = t >> 3, sslot = t & 7;
  const int sswz = sslot ^ (srow & 7);
  const char* kg = (const char*)(k + ((long)bh * T_ + srow) * HD_) + sswz * 16;
  const char* vg = (const char*)(vt + ((long)bh * HD_ + srow) * T_) + sswz * 16;

  auto stage = [&](int buf, int kv0) {
    char* Kd = (char*)Ks[buf] + w * 1024;
    char* Vd = (char*)Vs[buf] + w * 1024;
    gload_lds16(kg + (long)kv0 * 128, Kd);
    gload_lds16(kg + (long)kv0 * 128 + 32 * 128, Kd + 4096);
    gload_lds16(vg + (long)kv0 * 2, Vd);
    gload_lds16(vg + (long)kv0 * 2 + 32 * (long)T_ * 2, Vd + 4096);
  };

  stage(0, 0);
  __syncthreads();

  const int ntile = qt + 1;
  for (int it = 0; it < ntile; ++it) {
    const int cur = it & 1;
    if (it + 1 < ntile) stage(cur ^ 1, (it + 1) * 64);
    const char* Kc = (const char*)Ks[cur];
    const char* Vc = (const char*)Vs[cur];

    f32x4 s[4];
    __builtin_amdgcn_s_setprio(1);
#pragma unroll
    for (int nf = 0; nf < 4; ++nf) {
      const char* kb = Kc + (nf * 16 + r16) * 128;
      const bf16x8 b0 = *reinterpret_cast<const bf16x8*>(kb + ((g ^ (r16 & 7)) << 4));
      const bf16x8 b1 = *reinterpret_cast<const bf16x8*>(kb + (((4 + g) ^ (r16 & 7)) << 4));
      f32x4 z = (f32x4){0.f, 0.f, 0.f, 0.f};
      z = __builtin_amdgcn_mfma_f32_16x16x32_bf16(b0, aq0, z, 0, 0, 0);
      z = __builtin_amdgcn_mfma_f32_16x16x32_bf16(b1, aq1, z, 0, 0, 0);
      s[nf] = z;
    }
    __builtin_amdgcn_s_setprio(0);

    bf16x8 pa0, pa1;
    soft_side(s, lrun, it == qt, qbase - it * 64, g, r16, pa0, pa1);

    __builtin_amdgcn_s_setprio(1);
#pragma unroll
    for (int nf = 0; nf < 4; ++nf) {
      const char* vb = Vc + (nf * 16 + r16) * 128;
      const bf16x8 v0 = *reinterpret_cast<const bf16x8*>(vb + ((g ^ (r16 & 7)) << 4));
      const bf16x8 v1 = *reinterpret_cast<const bf16x8*>(vb + (((4 + g) ^ (r16 & 7)) << 4));
      oacc[nf] = __builtin_amdgcn_mfma_f32_16x16x32_bf16(pa0, v0, oacc[nf], 0, 0, 0);
      oacc[nf] = __builtin_amdgcn_mfma_f32_16x16x32_bf16(pa1, v1, oacc[nf], 0, 0, 0);
    }
    __builtin_amdgcn_s_setprio(0);
    __syncthreads();
  }

  lrun += __shfl_xor(lrun, 16, 64);
  lrun += __shfl_xor(lrun, 32, 64);
  const float inv = 1.f / lrun;
  float invq[4];
#pragma unroll
  for (int rr = 0; rr < 4; ++rr) invq[rr] = __shfl(inv, 4 * g + rr, 64);
  const int b = bh >> 4, h = bh & 15;
#pragma unroll
  for (int nf = 0; nf < 4; ++nf) {
    const int hd = nf * 16 + r16;
#pragma unroll
    for (int rr = 0; rr < 4; ++rr) {
      const int tt = qbase + g * 4 + rr;
      o[((long)b * T_ + tt) * D_ + h * HD_ + hd] = (__bf16)(oacc[nf][rr] * invq[rr]);
    }
  }
}

// ---------------------------------------------------------------- launcher
extern "C" void kernel_launch(void* const* d_in, const int* in_sizes, int n_in,
                              void* d_out, int out_size, void* d_ws, size_t ws_size,
                              hipStream_t stream) {
  (void)in_sizes; (void)n_in; (void)out_size; (void)ws_size;
  const float* x     = (const float*)d_in[0];
  const float* Wqkv  = (const float*)d_in[1];
  const float* bqkv  = (const float*)d_in[2];
  const float* Wproj = (const float*)d_in[3];
  const float* bproj = (const float*)d_in[4];
  float* out = (float*)d_out;

  const long MT = (long)B_ * T_;          // 8192
  __bf16* xb     = (__bf16*)d_ws;                    // [8192][1024]
  __bf16* wqkvt  = xb + MT * D_;                     // [3072][1024]
  __bf16* wprojt = wqkvt + (long)3 * D_ * D_;        // [1024][1024]
  __bf16* qkvb   = wprojt + (long)D_ * D_;           // q,k: [2][B][H][T][64]
  __bf16* vtb    = qkvb + (long)2 * B_ * H_ * T_ * HD_;  // [B][H][64][T]
  __bf16* attno  = vtb + (long)B_ * H_ * HD_ * T_;   // [8192][1024]

  k_cvt_f32_bf16<<<2048, 256, 0, stream>>>(x, xb, (int)(MT * D_ / 4));
  k_transpose_bf16<float><<<dim3(48, 16, 1), 256, 0, stream>>>(Wqkv, wqkvt, D_, 3 * D_, 0, 0);
  k_transpose_bf16<float><<<dim3(16, 16, 1), 256, 0, stream>>>(Wproj, wprojt, D_, D_, 0, 0);
  k_gemm_bt<0><<<dim3(24, 64), 256, 0, stream>>>(xb, wqkvt, bqkv, qkvb, vtb, 8192, 3072, 1024);
  k_attn<<<dim3(64, 32), 256, 0, stream>>>(
      qkvb, qkvb + (long)B_ * H_ * T_ * HD_, vtb, attno);
  k_gemm_bt<1><<<dim3(8, 64), 256, 0, stream>>>(attno, wprojt, bproj, out, nullptr, 8192, 1024, 1024);
}